// Round 2
// baseline (228.740 us; speedup 1.0000x reference)
//
#include <hip/hip_runtime.h>
#include <hip/hip_bf16.h>

#define H  32
#define W  32
#define CI 32
#define CO 64
#define NB 8
#define NOUT 32

// d_out float offsets: [w_u | b_u | w_l | b_l]
#define WU_OFF 0
#define BU_OFF (NB * H * W * CI * NOUT)          // 8388608
#define WL_OFF (BU_OFF + NB * NOUT)              // 8388864
#define BL_OFF (WL_OFF + NB * H * W * CI * NOUT) // 16777472

// d_ws layout:
//   [0, 36864)       bf16 A-fragments (2304 uint4)
//   [36864, 38912)   fp32 bias partials bp[16][32]
#define KF_UINT4 2304
#define BP_OFF_BYTES 36864

typedef __bf16 bf16x8 __attribute__((ext_vector_type(8)));
typedef float  f32x4  __attribute__((ext_vector_type(4)));

__device__ __forceinline__ unsigned int pack_bf16(float lo, float hi) {
    unsigned int ulo = __float_as_uint(lo) + 0x8000u;
    unsigned int uhi = __float_as_uint(hi) + 0x8000u;
    return (uhi & 0xffff0000u) | (ulo >> 16);
}

// Swizzle conv kernel K[3][3][32][64] fp32 -> bf16 A-fragments (HW-verified R1-R4).
// Blocks 9,10 zero the fp32 bias-partial buffer.
__global__ void prep_kernel(const float* __restrict__ K,
                            unsigned int* __restrict__ kws,
                            float* __restrict__ bp) {
    int bx = blockIdx.x, t = threadIdx.x;
    if (bx < 9) {
        int g    = bx * 256 + t;
        int tap  = g >> 8;
        int r    = g & 255;
        int i    = r >> 3;
        int og   = r & 7;
        int c    = og >> 2;
        int quad = og & 3;
        int ih   = i >> 4;
        int lane = quad * 16 + (i & 15);
        int dst  = ((tap * 4 + c * 2 + ih) * 64 + lane) * 4;
        const float4* src = (const float4*)(K + (size_t)g * 8);
        float4 f0 = src[0];
        float4 f1 = src[1];
        kws[dst + 0] = pack_bf16(f0.x, f0.y);
        kws[dst + 1] = pack_bf16(f0.z, f0.w);
        kws[dst + 2] = pack_bf16(f1.x, f1.y);
        kws[dst + 3] = pack_bf16(f1.z, f1.w);
    } else {
        bp[(bx - 9) * 256 + t] = 0.f;
    }
}

// Fused transpose+conv: one block per (side,b,h,w-half). Stages 3x18 halo
// tiles (co-half per c-pass) fp32->bf16 into XOR-swizzled LDS using the
// R1-verified vectorized read+pack, then runs the R3-verified MFMA phase
// reading B-fragments from LDS. Accumulators persist across the c-loop.
// Removes the 134 MB T round-trip: HBM demand 335 -> 201 MB.
// LDS: kf 36 KB + stg 108 KB + bias 256 B = 147.7 KB (1 block/CU, 8 waves).
__global__ __launch_bounds__(512, 2)
void fused_conv_kernel(const float* __restrict__ in0,
                       const float* __restrict__ in1,
                       const uint4* __restrict__ kws,
                       const float* __restrict__ bias,
                       float* __restrict__ bp,       // bp[16][32], pre-zeroed
                       float* __restrict__ out0,
                       float* __restrict__ out1) {
    __shared__ uint4 kf[KF_UINT4];        // 36864 B
    __shared__ uint4 stg[3 * 18 * 4 * 32]; // 110592 B: [row][col][og'][n^og']
    __shared__ float bias_s[CO];

    int t = threadIdx.x;
    for (int k = t; k < KF_UINT4; k += 512) kf[k] = kws[k];
    if (t < CO) bias_s[t] = bias[t];

    // XCD-aware swizzle: grid 1024, 8 XCDs, 2 (side,b) slabs/XCD, h-major
    // within slab so the 3-row fp32 window stays L2-resident for the c=1 pass.
    int bx    = blockIdx.x;
    int x     = bx & 7;
    int q     = bx >> 3;              // 0..127
    int combo = x * 2 + (q >> 6);     // (side,b) slab 0..15
    int idx   = q & 63;
    int side  = combo >> 3;
    int b     = combo & 7;
    int h     = idx >> 1;
    int wh    = idx & 1;

    const float* inp = (side ? in1 : in0) + (size_t)b * 1024 * 2048;

    // staging coords: unit stages one tile with 32 lanes
    int unit = t >> 5;        // 0..15
    int ogp  = (t >> 3) & 3;  // og' within co-half
    int n4   = t & 7;
    // mfma coords
    int wave = t >> 6;        // 0..7
    int lane = t & 63;
    int n16  = lane & 15;
    int quad = lane >> 4;

    f32x4 acc[2][2][2] = {};  // [pos][ih][nh]
    float sb[4] = {0.f, 0.f, 0.f, 0.f};
    const bf16x8* kfp = (const bf16x8*)kf;

    for (int c = 0; c < 2; c++) {
        __syncthreads();               // protects stg overwrite (and kf load at c=0)
        // ---- stage c-half of 54 halo tiles ----
        for (int s = 0; s < 4; s++) {
            int tile = s * 16 + unit;
            if (tile >= 54) break;
            int row = tile / 18;       // 0..2 -> hi = h-1+row
            int col = tile - row * 18; // 0..17 -> wi = wh*16-1+col
            int hi  = h - 1 + row;
            int wi  = wh * 16 - 1 + col;
            if (hi < 0 || hi >= H || wi < 0 || wi >= W) continue;
            const float* p = inp + (size_t)(hi * W + wi) * 2048
                           + c * 1024 + ogp * 256 + n4 * 4;
            float v[8][4];
#pragma unroll
            for (int j = 0; j < 8; j++) {
                float4 f = *(const float4*)(p + j * 32);   // 16 B/lane coalesced
                v[j][0] = f.x; v[j][1] = f.y; v[j][2] = f.z; v[j][3] = f.w;
            }
            // bias einsum on owned tiles only (each input pos owned by exactly
            // one block: row==1 and col in [1,16])
            if (row == 1 && col >= 1 && col <= 16) {
#pragma unroll
                for (int j = 0; j < 8; j++) {
                    float bj = bias_s[c * 32 + ogp * 8 + j];
#pragma unroll
                    for (int k = 0; k < 4; k++)
                        sb[k] = fmaf(v[j][k], bj, sb[k]);
                }
            }
            uint4* dst = &stg[tile * 128 + ogp * 32];
#pragma unroll
            for (int k = 0; k < 4; k++) {
                uint4 u;
                u.x = pack_bf16(v[0][k], v[1][k]);
                u.y = pack_bf16(v[2][k], v[3][k]);
                u.z = pack_bf16(v[4][k], v[5][k]);
                u.w = pack_bf16(v[6][k], v[7][k]);
                dst[(n4 * 4 + k) ^ ogp] = u;   // XOR-swizzle: conflict-free b128
            }
        }
        __syncthreads();
        // ---- MFMA phase for this c-half (R3-verified fragment maps) ----
#pragma unroll
        for (int p2 = 0; p2 < 2; p2++) {
            int wl = wave * 2 + p2;
            int w  = wh * 16 + wl;
#pragma unroll
            for (int kh = 0; kh < 3; kh++) {
                int hi = h + 1 - kh;
                if (hi < 0 || hi >= H) continue;
                int row = 2 - kh;
#pragma unroll
                for (int kw = 0; kw < 3; kw++) {
                    int wi = w + 1 - kw;
                    if (wi < 0 || wi >= W) continue;
                    int col = wl + 2 - kw;     // in [0,17]
                    int tap = kh * 3 + kw;
                    const uint4* Tp = &stg[(row * 18 + col) * 128];
                    union { uint4 u; bf16x8 v; } b0, b1;
                    b0.u = Tp[quad * 32 + (n16 ^ quad)];
                    b1.u = Tp[quad * 32 + (n16 ^ quad) + 16];
                    bf16x8 a0 = kfp[(tap * 4 + c * 2 + 0) * 64 + lane];
                    bf16x8 a1 = kfp[(tap * 4 + c * 2 + 1) * 64 + lane];
                    acc[p2][0][0] = __builtin_amdgcn_mfma_f32_16x16x32_bf16(a0, b0.v, acc[p2][0][0], 0, 0, 0);
                    acc[p2][0][1] = __builtin_amdgcn_mfma_f32_16x16x32_bf16(a0, b1.v, acc[p2][0][1], 0, 0, 0);
                    acc[p2][1][0] = __builtin_amdgcn_mfma_f32_16x16x32_bf16(a1, b0.v, acc[p2][1][0], 0, 0, 0);
                    acc[p2][1][1] = __builtin_amdgcn_mfma_f32_16x16x32_bf16(a1, b1.v, acc[p2][1][1], 0, 0, 0);
                }
            }
        }
    }

    // bias reduce over lane bits 3,4,5 (og' + unit parity), then atomics
#pragma unroll
    for (int off = 8; off <= 32; off <<= 1)
#pragma unroll
        for (int k = 0; k < 4; k++)
            sb[k] += __shfl_xor(sb[k], off, 64);
    if (lane < 8) {
#pragma unroll
        for (int k = 0; k < 4; k++)
            atomicAdd(&bp[side * 256 + b * 32 + n4 * 4 + k], sb[k]);
    }

    // store (same per-lane map as verified conv_t)
    float* outp = (side ? out1 : out0) + (size_t)b * (H * W * CI * NOUT);
#pragma unroll
    for (int p2 = 0; p2 < 2; p2++) {
        int w = wh * 16 + wave * 2 + p2;
        float* wout = outp + (size_t)((h * W + w) * CI) * NOUT;
#pragma unroll
        for (int ih = 0; ih < 2; ih++)
#pragma unroll
            for (int nh = 0; nh < 2; nh++)
#pragma unroll
                for (int r = 0; r < 4; r++) {
                    int i = ih * 16 + quad * 4 + r;
                    int n = nh * 16 + n16;
                    wout[i * NOUT + n] = acc[p2][ih][nh][r];
                }
    }
}

// Bias finalize: b = b_in + bp
__global__ void bias_final32_kernel(const float* __restrict__ bp,
                                    const float* __restrict__ bu,
                                    const float* __restrict__ bl,
                                    float* __restrict__ out) {
    int sb = blockIdx.x;             // 0..15
    int t  = threadIdx.x;
    if (t >= NOUT) return;
    int side = sb >> 3, b = sb & 7;
    const float* bb = side ? bl : bu;
    out[(side ? BL_OFF : BU_OFF) + b * NOUT + t] =
        bb[b * NOUT + t] + bp[sb * 32 + t];
}

extern "C" void kernel_launch(void* const* d_in, const int* in_sizes, int n_in,
                              void* d_out, int out_size, void* d_ws, size_t ws_size,
                              hipStream_t stream) {
    const float* wu   = (const float*)d_in[0];
    const float* bu   = (const float*)d_in[1];
    const float* wl   = (const float*)d_in[2];
    const float* bl   = (const float*)d_in[3];
    const float* K    = (const float*)d_in[4];
    const float* bias = (const float*)d_in[5];
    float* out = (float*)d_out;
    unsigned int* kws = (unsigned int*)d_ws;
    float* bp = (float*)((char*)d_ws + BP_OFF_BYTES);

    prep_kernel<<<dim3(11), dim3(256), 0, stream>>>(K, kws, bp);
    fused_conv_kernel<<<dim3(1024), dim3(512), 0, stream>>>(
        wu, wl, (const uint4*)d_ws, bias, bp, out + WU_OFF, out + WL_OFF);
    bias_final32_kernel<<<dim3(16), dim3(64), 0, stream>>>(bp, bu, bl, out);
}

// Round 3
// 219.849 us; speedup vs baseline: 1.0404x; 1.0404x over previous
//
#include <hip/hip_runtime.h>
#include <hip/hip_bf16.h>

#define H  32
#define W  32
#define CI 32
#define CO 64
#define NB 8
#define NOUT 32

// d_out float offsets: [w_u | b_u | w_l | b_l]
#define WU_OFF 0
#define BU_OFF (NB * H * W * CI * NOUT)          // 8388608
#define WL_OFF (BU_OFF + NB * NOUT)              // 8388864
#define BL_OFF (WL_OFF + NB * H * W * CI * NOUT) // 16777472

// d_ws layout:
//   [0, 36864)       bf16 A-fragments (2304 uint4)
//   [36864, 38912)   fp32 bias partials bp[16][32]
#define KF_UINT4 2304
#define BP_OFF_BYTES 36864

typedef __bf16 bf16x8 __attribute__((ext_vector_type(8)));
typedef float  f32x4  __attribute__((ext_vector_type(4)));

__device__ __forceinline__ unsigned int pack_bf16(float lo, float hi) {
    unsigned int ulo = __float_as_uint(lo) + 0x8000u;
    unsigned int uhi = __float_as_uint(hi) + 0x8000u;
    return (uhi & 0xffff0000u) | (ulo >> 16);
}

// Swizzle conv kernel K[3][3][32][64] fp32 -> bf16 A-fragments (HW-verified R1-R4).
// Blocks 9,10 zero the fp32 bias-partial buffer.
__global__ void prep_kernel(const float* __restrict__ K,
                            unsigned int* __restrict__ kws,
                            float* __restrict__ bp) {
    int bx = blockIdx.x, t = threadIdx.x;
    if (bx < 9) {
        int g    = bx * 256 + t;
        int tap  = g >> 8;
        int r    = g & 255;
        int i    = r >> 3;
        int og   = r & 7;
        int c    = og >> 2;
        int quad = og & 3;
        int ih   = i >> 4;
        int lane = quad * 16 + (i & 15);
        int dst  = ((tap * 4 + c * 2 + ih) * 64 + lane) * 4;
        const float4* src = (const float4*)(K + (size_t)g * 8);
        float4 f0 = src[0];
        float4 f1 = src[1];
        kws[dst + 0] = pack_bf16(f0.x, f0.y);
        kws[dst + 1] = pack_bf16(f0.z, f0.w);
        kws[dst + 2] = pack_bf16(f1.x, f1.y);
        kws[dst + 3] = pack_bf16(f1.z, f1.w);
    } else {
        bp[(bx - 9) * 256 + t] = 0.f;
    }
}

// Fused transpose+conv v2: 256-thread blocks, 8 w-positions each, 2 blocks/CU
// (stg 60 KB; kf moved to per-c register preload from global/L1 = 18 KB/half).
// Two independent barrier domains per CU overlap stage-phase with MFMA-phase.
// LDS swizzle slot = og'*32 + ((n ^ (n>>2)) ^ og'): conflict-free on BOTH the
// ds_write_b128 (k fixed, n4 varies -> 8 distinct slots per 8-lane group) and
// the ds_read_b128 (n16 varies -> 2-way = free per m136).
__global__ __launch_bounds__(256, 2)
void fused_conv_kernel(const float* __restrict__ in0,
                       const float* __restrict__ in1,
                       const uint4* __restrict__ kws,
                       const float* __restrict__ bias,
                       float* __restrict__ bp,       // bp[16][32], pre-zeroed
                       float* __restrict__ out0,
                       float* __restrict__ out1) {
    __shared__ uint4 stg[30 * 128];    // 61440 B: [row*10+col][128 swizzled]
    __shared__ float bias_s[CO];

    int t = threadIdx.x;
    if (t < CO) bias_s[t] = bias[t];

    // XCD-aware swizzle: 2048 blocks, XCD = bx&7 gets 2 contiguous (side,b)
    // slabs, h-major walk inside -> 3-row fp32 window stays L2-resident.
    int bx    = blockIdx.x;
    int x     = bx & 7;
    int q     = bx >> 3;              // 0..255
    int combo = x * 2 + (q >> 7);     // (side,b) 0..15
    int idx   = q & 127;
    int side  = combo >> 3;
    int b     = combo & 7;
    int h     = idx >> 2;
    int wq    = idx & 3;              // w-octet 0..3

    const float* inp = (side ? in1 : in0) + (size_t)b * 1024 * 2048;
    const bf16x8* kfp = (const bf16x8*)kws;

    // staging coords: unit (32 lanes) stages one tile
    int unit = t >> 5;        // 0..7
    int ogp  = (t >> 3) & 3;  // og' within co-half
    int n4   = t & 7;
    // mfma coords
    int wave = t >> 6;        // 0..3
    int lane = t & 63;
    int n16  = lane & 15;
    int quad = lane >> 4;

    f32x4 acc[2][2][2] = {};  // [pos][ih][nh]
    float sb[4] = {0.f, 0.f, 0.f, 0.f};
    int rbase = quad * 32 + ((n16 ^ (n16 >> 2)) ^ quad);   // b1 slot = rbase^20

    __syncthreads();          // bias_s ready

    for (int c = 0; c < 2; c++) {
        // ---- A-fragment preload for this c-half (issue early, L1-resident) ----
        bf16x8 a[9][2];
#pragma unroll
        for (int tap = 0; tap < 9; tap++) {
            a[tap][0] = kfp[(tap * 4 + c * 2 + 0) * 64 + lane];
            a[tap][1] = kfp[(tap * 4 + c * 2 + 1) * 64 + lane];
        }
        // ---- stage c-half of 30 halo tiles ----
        for (int s = 0; s < 4; s++) {
            int tile = s * 8 + unit;          // 0..31
            if (tile < 30) {
                int row = tile >= 20 ? 2 : (tile >= 10 ? 1 : 0);
                int col = tile - row * 10;    // 0..9
                int hi  = h - 1 + row;
                int wi  = wq * 8 - 1 + col;
                if (hi >= 0 && hi < H && wi >= 0 && wi < W) {
                    const float* p = inp + (size_t)(hi * W + wi) * 2048
                                   + c * 1024 + ogp * 256 + n4 * 4;
                    float v[8][4];
#pragma unroll
                    for (int j = 0; j < 8; j++) {
                        float4 f = *(const float4*)(p + j * 32);  // 16 B/lane
                        v[j][0] = f.x; v[j][1] = f.y; v[j][2] = f.z; v[j][3] = f.w;
                    }
                    // bias einsum on owned positions only (row==1, col 1..8)
                    if (row == 1 && col >= 1 && col <= 8) {
#pragma unroll
                        for (int j = 0; j < 8; j++) {
                            float bj = bias_s[c * 32 + ogp * 8 + j];
#pragma unroll
                            for (int k = 0; k < 4; k++)
                                sb[k] = fmaf(v[j][k], bj, sb[k]);
                        }
                    }
                    uint4* dst = &stg[tile * 128 + ogp * 32];
#pragma unroll
                    for (int k = 0; k < 4; k++) {
                        uint4 u;
                        u.x = pack_bf16(v[0][k], v[1][k]);
                        u.y = pack_bf16(v[2][k], v[3][k]);
                        u.z = pack_bf16(v[4][k], v[5][k]);
                        u.w = pack_bf16(v[6][k], v[7][k]);
                        int n = n4 * 4 + k;
                        dst[(n ^ (n >> 2)) ^ ogp] = u;
                    }
                }
            }
        }
        __syncthreads();
        // ---- MFMA phase (R2-verified fragment maps; A from regs) ----
        __builtin_amdgcn_s_setprio(1);
#pragma unroll
        for (int p2 = 0; p2 < 2; p2++) {
            int wl = wave * 2 + p2;           // 0..7
            int w  = wq * 8 + wl;
#pragma unroll
            for (int kh = 0; kh < 3; kh++) {
                int hi = h + 1 - kh;
                if (hi < 0 || hi >= H) continue;
                int row = 2 - kh;
#pragma unroll
                for (int kw = 0; kw < 3; kw++) {
                    int wi = w + 1 - kw;
                    if (wi < 0 || wi >= W) continue;
                    int col = wl + 2 - kw;    // 0..9
                    int tap = kh * 3 + kw;
                    const uint4* Tp = &stg[(row * 10 + col) * 128];
                    union { uint4 u; bf16x8 v; } b0, b1;
                    b0.u = Tp[rbase];
                    b1.u = Tp[rbase ^ 20];
                    acc[p2][0][0] = __builtin_amdgcn_mfma_f32_16x16x32_bf16(a[tap][0], b0.v, acc[p2][0][0], 0, 0, 0);
                    acc[p2][0][1] = __builtin_amdgcn_mfma_f32_16x16x32_bf16(a[tap][0], b1.v, acc[p2][0][1], 0, 0, 0);
                    acc[p2][1][0] = __builtin_amdgcn_mfma_f32_16x16x32_bf16(a[tap][1], b0.v, acc[p2][1][0], 0, 0, 0);
                    acc[p2][1][1] = __builtin_amdgcn_mfma_f32_16x16x32_bf16(a[tap][1], b1.v, acc[p2][1][1], 0, 0, 0);
                }
            }
        }
        __builtin_amdgcn_s_setprio(0);
        if (c == 0) __syncthreads();          // protect stg overwrite
    }

    // bias reduce over lane bits 3,4 (og') and 5 (unit parity), then atomics
#pragma unroll
    for (int off = 8; off <= 32; off <<= 1)
#pragma unroll
        for (int k = 0; k < 4; k++)
            sb[k] += __shfl_xor(sb[k], off, 64);
    if (lane < 8) {
#pragma unroll
        for (int k = 0; k < 4; k++)
            atomicAdd(&bp[side * 256 + b * 32 + n4 * 4 + k], sb[k]);
    }

    // store (same per-lane map as verified R2)
    float* outp = (side ? out1 : out0) + (size_t)b * (H * W * CI * NOUT);
#pragma unroll
    for (int p2 = 0; p2 < 2; p2++) {
        int w = wq * 8 + wave * 2 + p2;
        float* wout = outp + (size_t)((h * W + w) * CI) * NOUT;
#pragma unroll
        for (int ih = 0; ih < 2; ih++)
#pragma unroll
            for (int nh = 0; nh < 2; nh++)
#pragma unroll
                for (int r = 0; r < 4; r++) {
                    int i = ih * 16 + quad * 4 + r;
                    int n = nh * 16 + n16;
                    wout[i * NOUT + n] = acc[p2][ih][nh][r];
                }
    }
}

// Bias finalize: b = b_in + bp
__global__ void bias_final32_kernel(const float* __restrict__ bp,
                                    const float* __restrict__ bu,
                                    const float* __restrict__ bl,
                                    float* __restrict__ out) {
    int sb = blockIdx.x;             // 0..15
    int t  = threadIdx.x;
    if (t >= NOUT) return;
    int side = sb >> 3, b = sb & 7;
    const float* bb = side ? bl : bu;
    out[(side ? BL_OFF : BU_OFF) + b * NOUT + t] =
        bb[b * NOUT + t] + bp[sb * 32 + t];
}

extern "C" void kernel_launch(void* const* d_in, const int* in_sizes, int n_in,
                              void* d_out, int out_size, void* d_ws, size_t ws_size,
                              hipStream_t stream) {
    const float* wu   = (const float*)d_in[0];
    const float* bu   = (const float*)d_in[1];
    const float* wl   = (const float*)d_in[2];
    const float* bl   = (const float*)d_in[3];
    const float* K    = (const float*)d_in[4];
    const float* bias = (const float*)d_in[5];
    float* out = (float*)d_out;
    unsigned int* kws = (unsigned int*)d_ws;
    float* bp = (float*)((char*)d_ws + BP_OFF_BYTES);

    prep_kernel<<<dim3(11), dim3(256), 0, stream>>>(K, kws, bp);
    fused_conv_kernel<<<dim3(2048), dim3(256), 0, stream>>>(
        wu, wl, (const uint4*)d_ws, bias, bp, out + WU_OFF, out + WL_OFF);
    bias_final32_kernel<<<dim3(16), dim3(64), 0, stream>>>(bp, bu, bl, out);
}